// Round 6
// baseline (778.605 us; speedup 1.0000x reference)
//
#include <hip/hip_runtime.h>

#define NPB 98        // nodes per edge-block (CSR ownership; block range = [b*NPB, b*NPB+NPB))
#define TEK 128       // edges per tile in edge_csr_kernel (two 64-edge sub-tiles)
#define EBLK 1024
#define NBLK 512
#define TN 64

typedef float f32x4 __attribute__((ext_vector_type(4)));
typedef short s16x8 __attribute__((ext_vector_type(8)));

static __device__ __forceinline__ unsigned short f2bf(float f) {
    unsigned int u = __float_as_uint(f);
    u += 0x7FFFu + ((u >> 16) & 1u);          // round-to-nearest-even
    return (unsigned short)(u >> 16);
}
static __device__ __forceinline__ float bf2f(unsigned short s) {
    return __uint_as_float(((unsigned int)s) << 16);
}

// LDS-visibility barrier WITHOUT vmcnt drain: sched_barrier pins ordering,
// lgkmcnt(0) makes this wave's ds ops visible, raw s_barrier syncs.
// No "memory" clobber -> waitcnt pass does NOT insert vmcnt(0).
static __device__ __forceinline__ void bar_sync() {
    __builtin_amdgcn_sched_barrier(0);
    asm volatile("s_waitcnt lgkmcnt(0)");
    __builtin_amdgcn_s_barrier();
    __builtin_amdgcn_sched_barrier(0);
}

// ---------------------------------------------------------------------------
// Sort pipeline: counting sort of edges by dst.
// ---------------------------------------------------------------------------
__global__ void hist_kernel(const int* __restrict__ ei, int* __restrict__ cnt, int E) {
    int e = blockIdx.x * blockDim.x + threadIdx.x;
    if (e < E) atomicAdd(&cnt[ei[E + e]], 1);
}

__global__ __launch_bounds__(1024) void scan_kernel(int* __restrict__ cur,
                                                    int* __restrict__ rs, int N, int E) {
    __shared__ int s[1024];
    const int tid = threadIdx.x;
    const int chunk = (N + 1023) >> 10;
    const int base = tid * chunk;
    const int end  = min(base + chunk, N);
    int local = 0;
    for (int i = base; i < end; ++i) local += cur[i];
    s[tid] = local;
    __syncthreads();
    for (int off = 1; off < 1024; off <<= 1) {
        int v = (tid >= off) ? s[tid - off] : 0;
        __syncthreads();
        s[tid] += v;
        __syncthreads();
    }
    int run = s[tid] - local;   // exclusive prefix for this thread's chunk
    for (int i = base; i < end; ++i) {
        int c = cur[i];
        rs[i]  = run;
        cur[i] = run;           // cursor for scatter
        run += c;
    }
    if (tid == 0) rs[N] = E;
}

__global__ void scatter_kernel(const int* __restrict__ ei, int* __restrict__ cur,
                               int* __restrict__ meta, int* __restrict__ srcs, int E) {
    int e = blockIdx.x * blockDim.x + threadIdx.x;
    if (e < E) {
        int d   = ei[E + e];
        int pos = atomicAdd(&cur[d], 1);
        meta[pos] = ((d % NPB) << 20) | e;   // dloc[6:0] | eid[19:0]
        srcs[pos] = ei[e];
    }
}

// ---------------------------------------------------------------------------
// Edge kernel, CSR / owned-range: block b owns nodes [b*NPB, b*NPB+NPB).
// Per 128-edge tile (2 x 64-edge sub-tiles, 8 waves each):
//  A: read src/dloc(t) | gather x(t) | prefetch meta/ea/src(t+1) | h(t) f32
//  BAR (lgkm only)
//  B: MFMA split-3 (t) | LDS-stage(t+1) | ds_add into LDS accum
//  BAR (lgkm only)
// No global atomics. Flush accum -> agg with plain stores.
// LDS ~152KB -> 1 block/CU (16 waves).
// ---------------------------------------------------------------------------
__global__ __launch_bounds__(EBLK, 4) void edge_csr_kernel(
    const float* __restrict__ x,     // [N][96]
    const float* __restrict__ ea,    // [E][17]
    const float* __restrict__ W1,    // [96][17]
    const float* __restrict__ b1,    // [96]
    const float* __restrict__ W2,    // [96][96]
    const float* __restrict__ b2,    // [96]
    const int*   __restrict__ rs,    // [N+1] row_start
    const int*   __restrict__ meta,  // [E] (dloc<<20)|eid, dst-sorted
    const int*   __restrict__ srcs,  // [E] src, dst-sorted
    float* agg,                      // [N][96] (may be d_out)
    int N, int E)
{
    __shared__ unsigned short sBh[9216], sBl[9216];   // W2 hi/lo, fragment-linear
    __shared__ unsigned short sAh[3][TEK][40];        // h hi, chunk-major
    __shared__ unsigned short sAl[3][TEK][40];        // h lo
    __shared__ float sW1[96][20];
    __shared__ float sea[TEK][20];
    __shared__ float accum[NPB][96];
    __shared__ float sb1[96];
    __shared__ int   s_src[TEK], s_dloc[TEK];

    const int tid  = threadIdx.x;
    const int c    = tid & 31;             // h-phase d-lane
    const int g    = (tid >> 5) & 15;      // h-phase edge subgroup (within sub)
    const int sub  = tid >> 9;             // 0/1 : which 64-edge sub-tile
    const int es0  = sub * 64;
    const int lane = tid & 63;
    const int wv8  = (tid >> 6) & 7;       // wave within sub
    const int mr   = wv8 & 3;
    const int ng   = wv8 >> 2;
    const int l15  = lane & 15;
    const int l4   = lane >> 4;

    const int nb0    = blockIdx.x * NPB;
    const int ebeg   = rs[min(nb0, N)];
    const int eend   = rs[min(nb0 + NPB, N)];
    const int ecount = eend - ebeg;
    const int ntiles = (ecount + TEK - 1) / TEK;

    // ---- one-time staging ----
    for (int idx = tid; idx < 96 * 20; idx += EBLK) {
        int d = idx / 20, k = idx - d * 20;
        sW1[d][k] = (k < 17) ? W1[d * 17 + k] : 0.f;
    }
    for (int idx = tid; idx < 96 * 96; idx += EBLK) {
        int d = idx / 96, k = idx - d * 96;
        float v = W2[idx];
        unsigned short hb = f2bf(v);
        int ngf = d / 48, tt = (d % 48) / 16, r = d & 15;
        int ch = k >> 5, kl4 = (k & 31) >> 3, sb = k & 7;
        int fo = ((((ngf * 3 + tt) * 3 + ch) * 4 + kl4) * 16 + r) * 8 + sb;
        sBh[fo] = hb;
        sBl[fo] = f2bf(v - bf2f(hb));
    }
    if (tid < 96) sb1[tid] = b1[tid];
    if (tid < TEK) { sea[tid][17] = 0.f; sea[tid][18] = 0.f; sea[tid][19] = 0.f; }
    for (int idx = tid; idx < NPB * 96; idx += EBLK) (&accum[0][0])[idx] = 0.f;

    float bias[3]; int dv[3];
    #pragma unroll
    for (int t = 0; t < 3; ++t) {
        dv[t]   = (ng * 3 + t) * 16 + l15;
        bias[t] = b2[dv[t]];
    }

    // ---- prologue: prefetch tile 0 ----
    const int pe = tid >> 3, ps = tid & 7;
    float pf0 = 0.f, pf1 = 0.f, pf2 = 0.f;
    int sp_src = 0, sp_meta = 0;
    if (ntiles > 0) {
        int gi = min(ebeg + pe, E - 1);
        int m  = meta[gi];
        const float* er = ea + (size_t)(m & 0xFFFFF) * 17;
        pf0 = er[ps];
        pf1 = er[ps + 8];
        if (ps == 0) pf2 = er[16];
        if (tid < TEK) {
            int gj = min(ebeg + tid, E - 1);
            sp_meta = meta[gj];
            sp_src  = srcs[gj];
        }
    }
    __syncthreads();
    if (ntiles > 0) {
        sea[pe][ps]     = pf0;
        sea[pe][ps + 8] = pf1;
        if (ps == 0) sea[pe][16] = pf2;
        if (tid < TEK) { s_src[tid] = sp_src; s_dloc[tid] = sp_meta >> 20; }
    }
    __syncthreads();

    for (int t = 0; t < ntiles; ++t) {
        const bool nxt = (t + 1) < ntiles;
        const int  rem = ecount - t * TEK;

        // ===== Phase A =====
        int sg[4], dl[4];
        #pragma unroll
        for (int j = 0; j < 4; ++j) {
            int el = es0 + mr * 16 + l4 * 4 + j;
            sg[j] = s_src[el];
            dl[j] = s_dloc[el];
        }
        float xg[12];
        #pragma unroll
        for (int tt = 0; tt < 3; ++tt)
            #pragma unroll
            for (int j = 0; j < 4; ++j)
                xg[tt * 4 + j] = x[(size_t)sg[j] * 96 + dv[tt]];

        if (nxt) {
            int gi = min(ebeg + (t + 1) * TEK + pe, E - 1);
            int m  = meta[gi];
            const float* er = ea + (size_t)(m & 0xFFFFF) * 17;
            pf0 = er[ps];
            pf1 = er[ps + 8];
            if (ps == 0) pf2 = er[16];
            if (tid < TEK) {
                int gj = min(ebeg + (t + 1) * TEK + tid, E - 1);
                sp_meta = meta[gj];
                sp_src  = srcs[gj];
            }
        }

        // h = relu(ea @ W1^T + b1) -> bf16 hi/lo into sA
        {
            float hacc[4][3];
            #pragma unroll
            for (int i = 0; i < 4; ++i) {
                hacc[i][0] = sb1[c]; hacc[i][1] = sb1[c + 32]; hacc[i][2] = sb1[c + 64];
            }
            #pragma unroll
            for (int k0 = 0; k0 < 20; k0 += 4) {
                float4 w0 = *(const float4*)&sW1[c][k0];
                float4 w1 = *(const float4*)&sW1[c + 32][k0];
                float4 w2 = *(const float4*)&sW1[c + 64][k0];
                #pragma unroll
                for (int i = 0; i < 4; ++i) {
                    float4 av = *(const float4*)&sea[es0 + g * 4 + i][k0];
                    hacc[i][0] = fmaf(av.w, w0.w, fmaf(av.z, w0.z, fmaf(av.y, w0.y, fmaf(av.x, w0.x, hacc[i][0]))));
                    hacc[i][1] = fmaf(av.w, w1.w, fmaf(av.z, w1.z, fmaf(av.y, w1.y, fmaf(av.x, w1.x, hacc[i][1]))));
                    hacc[i][2] = fmaf(av.w, w2.w, fmaf(av.z, w2.z, fmaf(av.y, w2.y, fmaf(av.x, w2.x, hacc[i][2]))));
                }
            }
            #pragma unroll
            for (int i = 0; i < 4; ++i) {
                int e = es0 + g * 4 + i;
                #pragma unroll
                for (int j = 0; j < 3; ++j) {
                    float v = fmaxf(hacc[i][j], 0.f);
                    unsigned short hb = f2bf(v);
                    sAh[j][e][c] = hb;
                    sAl[j][e][c] = f2bf(v - bf2f(hb));
                }
            }
        }
        bar_sync();   // BAR1: sA visible; vmcnt NOT drained

        // ===== Phase B =====
        f32x4 acc[3];
        #pragma unroll
        for (int t3 = 0; t3 < 3; ++t3) acc[t3] = (f32x4){0.f, 0.f, 0.f, 0.f};
        const int arow = es0 + mr * 16 + l15;
        #pragma unroll
        for (int chunk = 0; chunk < 3; ++chunk) {
            s16x8 a_hi = *(const s16x8*)&sAh[chunk][arow][l4 * 8];
            s16x8 a_lo = *(const s16x8*)&sAl[chunk][arow][l4 * 8];
            #pragma unroll
            for (int t3 = 0; t3 < 3; ++t3) {
                const int base = (((ng * 3 + t3) * 3 + chunk) * 64 + lane) * 8;
                s16x8 b_hi = *(const s16x8*)&sBh[base];
                s16x8 b_lo = *(const s16x8*)&sBl[base];
                acc[t3] = __builtin_amdgcn_mfma_f32_16x16x32_bf16(a_hi, b_hi, acc[t3], 0, 0, 0);
                acc[t3] = __builtin_amdgcn_mfma_f32_16x16x32_bf16(a_hi, b_lo, acc[t3], 0, 0, 0);
                acc[t3] = __builtin_amdgcn_mfma_f32_16x16x32_bf16(a_lo, b_hi, acc[t3], 0, 0, 0);
            }
        }

        // stage tile t+1 (counted vmcnt waits for pf regs only)
        if (nxt) {
            sea[pe][ps]     = pf0;
            sea[pe][ps + 8] = pf1;
            if (ps == 0) sea[pe][16] = pf2;
            if (tid < TEK) { s_src[tid] = sp_src; s_dloc[tid] = sp_meta >> 20; }
        }

        // epilogue: accumulate messages into LDS (no global atomics)
        #pragma unroll
        for (int t3 = 0; t3 < 3; ++t3)
            #pragma unroll
            for (int j = 0; j < 4; ++j) {
                int el = es0 + mr * 16 + l4 * 4 + j;
                if (el < rem)
                    atomicAdd(&accum[dl[j]][dv[t3]], (acc[t3][j] + bias[t3]) * xg[t3 * 4 + j]);
            }

        bar_sync();   // BAR2: tile t+1 stage visible
    }

    __syncthreads();
    // flush owned node range with plain coalesced stores
    for (int idx = tid; idx < NPB * 96; idx += EBLK) {
        int n = nb0 + idx / 96;
        if (n < N) agg[(size_t)n * 96 + (idx % 96)] = (&accum[0][0])[idx];
    }
}

// ---------------------------------------------------------------------------
// Fallback edge kernel (round-4 atomic version) when ws is too small.
// ---------------------------------------------------------------------------
__global__ __launch_bounds__(512, 4) void edge_kernel_atomic(
    const float* __restrict__ x, const int* __restrict__ ei,
    const float* __restrict__ ea, const float* __restrict__ W1,
    const float* __restrict__ b1, const float* __restrict__ W2,
    const float* __restrict__ b2, float* __restrict__ agg, int N, int E)
{
    __shared__ unsigned short sBh[9216], sBl[9216];
    __shared__ unsigned short sAh[3][64][40], sAl[3][64][40];
    __shared__ float sW1[96][20];
    __shared__ float sea[64][20];
    __shared__ float sb1[96];
    __shared__ int   ssrc[64], sdst[64];

    const int tid = threadIdx.x;
    const int c = tid & 31, g = tid >> 5;
    const int lane = tid & 63, wv = tid >> 6;
    const int mr = wv & 3, ng = wv >> 2;
    const int l15 = lane & 15, l4 = lane >> 4;
    const int ntiles = (E + 63) / 64;

    for (int idx = tid; idx < 96 * 20; idx += 512) {
        int d = idx / 20, k = idx - d * 20;
        sW1[d][k] = (k < 17) ? W1[d * 17 + k] : 0.f;
    }
    for (int idx = tid; idx < 96 * 96; idx += 512) {
        int d = idx / 96, k = idx - d * 96;
        float v = W2[idx];
        unsigned short hb = f2bf(v);
        int ngf = d / 48, tt = (d % 48) / 16, r = d & 15;
        int ch = k >> 5, kl4 = (k & 31) >> 3, sb = k & 7;
        int fo = ((((ngf * 3 + tt) * 3 + ch) * 4 + kl4) * 16 + r) * 8 + sb;
        sBh[fo] = hb; sBl[fo] = f2bf(v - bf2f(hb));
    }
    if (tid < 96) sb1[tid] = b1[tid];
    float bias[3]; int dv[3];
    #pragma unroll
    for (int t = 0; t < 3; ++t) { dv[t] = (ng * 3 + t) * 16 + l15; bias[t] = b2[dv[t]]; }

    for (int tile = blockIdx.x; tile < ntiles; tile += 512) {
        const int e0 = tile * 64;
        __syncthreads();
        for (int idx = tid; idx < 64 * 20; idx += 512) {
            int e = idx / 20, k = idx - e * 20;
            float v = 0.f;
            if (k < 17 && e0 + e < E) v = ea[(size_t)(e0 + e) * 17 + k];
            sea[e][k] = v;
        }
        if (tid < 64) {
            int e = e0 + tid;
            ssrc[tid] = (e < E) ? ei[e] : 0;
            sdst[tid] = (e < E) ? ei[E + e] : 0;
        }
        __syncthreads();
        {
            float hacc[4][3];
            #pragma unroll
            for (int i = 0; i < 4; ++i) { hacc[i][0]=sb1[c]; hacc[i][1]=sb1[c+32]; hacc[i][2]=sb1[c+64]; }
            #pragma unroll
            for (int k0 = 0; k0 < 20; k0 += 4) {
                float4 w0 = *(const float4*)&sW1[c][k0];
                float4 w1 = *(const float4*)&sW1[c + 32][k0];
                float4 w2 = *(const float4*)&sW1[c + 64][k0];
                #pragma unroll
                for (int i = 0; i < 4; ++i) {
                    float4 av = *(const float4*)&sea[g * 4 + i][k0];
                    hacc[i][0] = fmaf(av.w, w0.w, fmaf(av.z, w0.z, fmaf(av.y, w0.y, fmaf(av.x, w0.x, hacc[i][0]))));
                    hacc[i][1] = fmaf(av.w, w1.w, fmaf(av.z, w1.z, fmaf(av.y, w1.y, fmaf(av.x, w1.x, hacc[i][1]))));
                    hacc[i][2] = fmaf(av.w, w2.w, fmaf(av.z, w2.z, fmaf(av.y, w2.y, fmaf(av.x, w2.x, hacc[i][2]))));
                }
            }
            #pragma unroll
            for (int i = 0; i < 4; ++i) {
                int e = g * 4 + i;
                #pragma unroll
                for (int j = 0; j < 3; ++j) {
                    float v = fmaxf(hacc[i][j], 0.f);
                    unsigned short hb = f2bf(v);
                    sAh[j][e][c] = hb; sAl[j][e][c] = f2bf(v - bf2f(hb));
                }
            }
        }
        __syncthreads();
        f32x4 acc[3];
        #pragma unroll
        for (int t = 0; t < 3; ++t) acc[t] = (f32x4){0.f, 0.f, 0.f, 0.f};
        const int arow = mr * 16 + l15;
        #pragma unroll
        for (int chunk = 0; chunk < 3; ++chunk) {
            s16x8 a_hi = *(const s16x8*)&sAh[chunk][arow][l4 * 8];
            s16x8 a_lo = *(const s16x8*)&sAl[chunk][arow][l4 * 8];
            #pragma unroll
            for (int t = 0; t < 3; ++t) {
                const int base = (((ng * 3 + t) * 3 + chunk) * 64 + lane) * 8;
                s16x8 b_hi = *(const s16x8*)&sBh[base];
                s16x8 b_lo = *(const s16x8*)&sBl[base];
                acc[t] = __builtin_amdgcn_mfma_f32_16x16x32_bf16(a_hi, b_hi, acc[t], 0, 0, 0);
                acc[t] = __builtin_amdgcn_mfma_f32_16x16x32_bf16(a_hi, b_lo, acc[t], 0, 0, 0);
                acc[t] = __builtin_amdgcn_mfma_f32_16x16x32_bf16(a_lo, b_hi, acc[t], 0, 0, 0);
            }
        }
        #pragma unroll
        for (int t = 0; t < 3; ++t)
            #pragma unroll
            for (int j = 0; j < 4; ++j) {
                int el = mr * 16 + l4 * 4 + j;
                int e  = e0 + el;
                if (e < E) {
                    int s = ssrc[el], dn = sdst[el];
                    atomicAdd(&agg[(size_t)dn * 96 + dv[t]],
                              (acc[t][j] + bias[t]) * x[(size_t)s * 96 + dv[t]]);
                }
            }
    }
}

// ---------------------------------------------------------------------------
// Node kernel: out = relu(x @ Ws^T + bs + agg @ Wn^T + bn).
// NOTE: agg may alias out (reads own rows into LDS before writing) -> no restrict.
// ---------------------------------------------------------------------------
__global__ __launch_bounds__(NBLK, 4) void node_kernel(
    const float* __restrict__ x,
    const float* agg,
    const float* __restrict__ Ws, const float* __restrict__ bs,
    const float* __restrict__ Wn, const float* __restrict__ bn,
    float* out, int N)
{
    __shared__ float sW[96][100];
    __shared__ float sxa[TN][100];
    __shared__ float sbias[96];

    const int tid = threadIdx.x;
    const int c = tid & 31, g = tid >> 5;
    const int n0 = blockIdx.x * TN;

    if (tid < 96) sbias[tid] = bs[tid] + bn[tid];

    float acc[4][3];
    #pragma unroll
    for (int i = 0; i < 4; ++i)
        for (int j = 0; j < 3; ++j) acc[i][j] = 0.f;

    for (int ph = 0; ph < 2; ++ph) {
        const float* W   = ph ? Wn : Ws;
        const float* src = ph ? agg : x;
        __syncthreads();
        for (int idx = tid; idx < 96 * 24; idx += NBLK) {
            int d = idx / 24, kq = idx - d * 24;
            *(float4*)&sW[d][kq * 4] = *(const float4*)&W[d * 96 + kq * 4];
        }
        for (int idx = tid; idx < TN * 24; idx += NBLK) {
            int n = idx / 24, kq = idx - n * 24;
            float4 v = make_float4(0.f, 0.f, 0.f, 0.f);
            if (n0 + n < N) v = *(const float4*)&src[(size_t)(n0 + n) * 96 + kq * 4];
            *(float4*)&sxa[n][kq * 4] = v;
        }
        __syncthreads();
        #pragma unroll 2
        for (int k0 = 0; k0 < 96; k0 += 4) {
            float4 w0 = *(const float4*)&sW[c][k0];
            float4 w1 = *(const float4*)&sW[c + 32][k0];
            float4 w2 = *(const float4*)&sW[c + 64][k0];
            #pragma unroll
            for (int i = 0; i < 4; ++i) {
                float4 xv = *(const float4*)&sxa[g * 4 + i][k0];
                acc[i][0] = fmaf(xv.w, w0.w, fmaf(xv.z, w0.z, fmaf(xv.y, w0.y, fmaf(xv.x, w0.x, acc[i][0]))));
                acc[i][1] = fmaf(xv.w, w1.w, fmaf(xv.z, w1.z, fmaf(xv.y, w1.y, fmaf(xv.x, w1.x, acc[i][1]))));
                acc[i][2] = fmaf(xv.w, w2.w, fmaf(xv.z, w2.z, fmaf(xv.y, w2.y, fmaf(xv.x, w2.x, acc[i][2]))));
            }
        }
    }

    #pragma unroll
    for (int i = 0; i < 4; ++i) {
        int n = n0 + g * 4 + i;
        if (n < N) {
            out[(size_t)n * 96 + c]      = fmaxf(acc[i][0] + sbias[c], 0.f);
            out[(size_t)n * 96 + c + 32] = fmaxf(acc[i][1] + sbias[c + 32], 0.f);
            out[(size_t)n * 96 + c + 64] = fmaxf(acc[i][2] + sbias[c + 64], 0.f);
        }
    }
}

extern "C" void kernel_launch(void* const* d_in, const int* in_sizes, int n_in,
                              void* d_out, int out_size, void* d_ws, size_t ws_size,
                              hipStream_t stream) {
    const float* x  = (const float*)d_in[0];
    const int*   ei = (const int*)d_in[1];
    const float* ea = (const float*)d_in[2];
    const float* W1 = (const float*)d_in[3];
    const float* b1 = (const float*)d_in[4];
    const float* W2 = (const float*)d_in[5];
    const float* b2 = (const float*)d_in[6];
    const float* Ws = (const float*)d_in[7];
    const float* bs = (const float*)d_in[8];
    const float* Wn = (const float*)d_in[9];
    const float* bn = (const float*)d_in[10];
    float* out = (float*)d_out;

    const int N = in_sizes[0] / 96;
    const int E = in_sizes[2] / 17;

    const size_t need = ((size_t)2 * N + 1 + (size_t)2 * E) * sizeof(int);
    if (ws_size >= need) {
        int* rs   = (int*)d_ws;          // [N+1] row_start
        int* cur  = rs + (N + 1);        // [N]   counts -> cursor
        int* meta = cur + N;             // [E]   (dloc<<20)|eid
        int* srcs = meta + E;            // [E]   src node ids

        hipMemsetAsync(cur, 0, (size_t)N * sizeof(int), stream);
        hist_kernel<<<(E + 255) / 256, 256, 0, stream>>>(ei, cur, E);
        scan_kernel<<<1, 1024, 0, stream>>>(cur, rs, N, E);
        scatter_kernel<<<(E + 255) / 256, 256, 0, stream>>>(ei, cur, meta, srcs, E);
        // agg lives in d_out (node_kernel reads its own rows before overwriting)
        edge_csr_kernel<<<(N + NPB - 1) / NPB, EBLK, 0, stream>>>(
            x, ea, W1, b1, W2, b2, rs, meta, srcs, out, N, E);
        node_kernel<<<(N + TN - 1) / TN, NBLK, 0, stream>>>(x, out, Ws, bs, Wn, bn, out, N);
    } else {
        // fallback: atomic path, agg in d_out
        hipMemsetAsync(out, 0, (size_t)N * 96 * sizeof(float), stream);
        edge_kernel_atomic<<<512, 512, 0, stream>>>(x, ei, ea, W1, b1, W2, b2, out, N, E);
        node_kernel<<<(N + TN - 1) / TN, NBLK, 0, stream>>>(x, out, Ws, bs, Wn, bn, out, N);
    }
}

// Round 7
// 425.543 us; speedup vs baseline: 1.8297x; 1.8297x over previous
//
#include <hip/hip_runtime.h>

#define BLOCK 512
#define TE 64    // edges per tile
#define TN 64    // nodes per tile (node kernel)
#define NTB 512  // edge grid blocks (2 per CU)

typedef float f32x4 __attribute__((ext_vector_type(4)));
typedef short s16x8 __attribute__((ext_vector_type(8)));

static __device__ __forceinline__ unsigned short f2bf(float f) {
    unsigned int u = __float_as_uint(f);
    u += 0x7FFFu + ((u >> 16) & 1u);          // round-to-nearest-even
    return (unsigned short)(u >> 16);
}
static __device__ __forceinline__ float bf2f(unsigned short s) {
    return __uint_as_float(((unsigned int)s) << 16);
}

// LDS-visibility barrier WITHOUT vmcnt drain (no "memory" clobber).
static __device__ __forceinline__ void bar_sync() {
    __builtin_amdgcn_sched_barrier(0);
    asm volatile("s_waitcnt lgkmcnt(0)");
    __builtin_amdgcn_s_barrier();
    __builtin_amdgcn_sched_barrier(0);
}

// ---------------------------------------------------------------------------
// Counting sort of edges by dst.
// ---------------------------------------------------------------------------
__global__ void hist_kernel(const int* __restrict__ ei, int* __restrict__ cnt, int E) {
    int e = blockIdx.x * blockDim.x + threadIdx.x;
    if (e < E) atomicAdd(&cnt[ei[E + e]], 1);
}

__global__ __launch_bounds__(1024) void scan_kernel(int* __restrict__ cur, int N) {
    __shared__ int s[1024];
    const int tid = threadIdx.x;
    const int chunk = (N + 1023) >> 10;
    const int base = tid * chunk;
    const int end  = min(base + chunk, N);
    int local = 0;
    for (int i = base; i < end; ++i) local += cur[i];
    s[tid] = local;
    __syncthreads();
    for (int off = 1; off < 1024; off <<= 1) {
        int v = (tid >= off) ? s[tid - off] : 0;
        __syncthreads();
        s[tid] += v;
        __syncthreads();
    }
    int run = s[tid] - local;   // exclusive prefix
    for (int i = base; i < end; ++i) {
        int c = cur[i];
        cur[i] = run;           // cursor for scatter
        run += c;
    }
}

// 8 threads per edge: coalesced ea copy into sorted order + packed (dst<<16)|src.
__global__ __launch_bounds__(512) void scatter_kernel(
    const int* __restrict__ ei, const float* __restrict__ ea,
    int* __restrict__ cur, unsigned* __restrict__ packed,
    float* __restrict__ ea_s, int E)
{
    int t = blockIdx.x * blockDim.x + threadIdx.x;
    int e = t >> 3, ps = t & 7;
    if (e >= E) return;
    int lane = threadIdx.x & 63;
    int pos = 0;
    if (ps == 0) {
        int d = ei[E + e], s = ei[e];
        pos = atomicAdd(&cur[d], 1);
        packed[pos] = ((unsigned)d << 16) | (unsigned)s;
    }
    pos = __shfl(pos, lane & 56, 64);   // broadcast within 8-lane group
    const float* er = ea + (size_t)e * 17;
    float* wr = ea_s + (size_t)pos * 17;
    wr[ps]     = er[ps];
    wr[ps + 8] = er[ps + 8];
    if (ps == 0) wr[16] = er[16];
}

// ---------------------------------------------------------------------------
// Edge kernel over dst-sorted edges; register segmented-merge before atomics.
//  A: read src/dst(t)->regs | gather x(t) | prefetch packed/ea(t+1) (static!) | h(t)
//  BAR (lgkm only)
//  B: MFMA split-3 | stage(t+1) | v=(acc+bias)*xg | run-merge | few atomics (ride)
//  BAR (lgkm only)
// ---------------------------------------------------------------------------
__global__ __launch_bounds__(BLOCK, 4) void edge_sorted_kernel(
    const float* __restrict__ x,          // [N][96]
    const unsigned* __restrict__ packed,  // [E] (dst<<16)|src, dst-sorted
    const float* __restrict__ ea_s,       // [E][17] dst-sorted
    const float* __restrict__ W1, const float* __restrict__ b1,
    const float* __restrict__ W2, const float* __restrict__ b2,
    float* agg, int N, int E)
{
    __shared__ unsigned short sBh[9216], sBl[9216];   // W2 hi/lo, fragment-linear
    __shared__ unsigned short sAh[3][TE][40];         // h hi, chunk-major
    __shared__ unsigned short sAl[3][TE][40];         // h lo
    __shared__ float sW1[96][20];
    __shared__ float sea[TE][20];
    __shared__ float sb1[96];
    __shared__ int   s_src[TE], s_dst[TE];

    const int tid  = threadIdx.x;
    const int c    = tid & 31;
    const int g    = tid >> 5;
    const int lane = tid & 63;
    const int wv   = tid >> 6;
    const int mr   = wv & 3;
    const int ng   = wv >> 2;
    const int l15  = lane & 15;
    const int l4   = lane >> 4;

    const int ntiles = (E + TE - 1) / TE;

    // ---- prefetch tile0 (flies under weight staging) ----
    const int pe = tid >> 3, ps = tid & 7;
    float pf0 = 0.f, pf1 = 0.f, pf2 = 0.f; unsigned pk = 0;
    int tile = blockIdx.x;
    {
        int r = min(tile * TE + pe, E - 1);
        const float* er = ea_s + (size_t)r * 17;
        pf0 = er[ps];
        pf1 = er[ps + 8];
        if (ps == 0) pf2 = er[16];
        if (tid < TE) pk = packed[min(tile * TE + tid, E - 1)];
    }

    // ---- one-time staging ----
    for (int idx = tid; idx < 96 * 20; idx += BLOCK) {
        int d = idx / 20, k = idx - d * 20;
        sW1[d][k] = (k < 17) ? W1[d * 17 + k] : 0.f;
    }
    for (int idx = tid; idx < 96 * 96; idx += BLOCK) {
        int d = idx / 96, k = idx - d * 96;
        float v = W2[idx];
        unsigned short hb = f2bf(v);
        int ngf = d / 48, tt = (d % 48) / 16, r = d & 15;
        int ch = k >> 5, kl4 = (k & 31) >> 3, sb = k & 7;
        int fo = ((((ngf * 3 + tt) * 3 + ch) * 4 + kl4) * 16 + r) * 8 + sb;
        sBh[fo] = hb;
        sBl[fo] = f2bf(v - bf2f(hb));
    }
    if (tid < 96) sb1[tid] = b1[tid];
    if (tid < TE) { sea[tid][17] = 0.f; sea[tid][18] = 0.f; sea[tid][19] = 0.f; }

    float bias[3]; int dv[3];
    #pragma unroll
    for (int t = 0; t < 3; ++t) {
        dv[t]   = (ng * 3 + t) * 16 + l15;
        bias[t] = b2[dv[t]];
    }

    __syncthreads();   // weights staged, tile0 prefetch drained
    sea[pe][ps]     = pf0;
    sea[pe][ps + 8] = pf1;
    if (ps == 0) sea[pe][16] = pf2;
    if (tid < TE) {
        int e = tile * TE + tid;
        s_dst[tid] = (e < E) ? (int)(pk >> 16) : -1;
        s_src[tid] = (int)(pk & 0xFFFFu);
    }
    __syncthreads();

    for (; tile < ntiles; tile += NTB) {
        const int nxt = tile + NTB;

        // ===== Phase A =====
        const int g16 = mr * 16;
        int sg[4], dj[4];
        #pragma unroll
        for (int j = 0; j < 4; ++j) {
            int el = g16 + l4 * 4 + j;
            sg[j] = s_src[el];
            dj[j] = s_dst[el];
        }
        const int dFirst = s_dst[g16], dLast = s_dst[g16 + 15];

        // gathers (oldest VMEM this iteration)
        float xg[12];
        #pragma unroll
        for (int t3 = 0; t3 < 3; ++t3)
            #pragma unroll
            for (int j = 0; j < 4; ++j)
                xg[t3 * 4 + j] = x[(size_t)sg[j] * 96 + dv[t3]];

        // prefetch tile t+1 (STATIC addresses -> no pointer chase)
        if (nxt < ntiles) {
            int r = min(nxt * TE + pe, E - 1);
            const float* er = ea_s + (size_t)r * 17;
            pf0 = er[ps];
            pf1 = er[ps + 8];
            if (ps == 0) pf2 = er[16];
            if (tid < TE) pk = packed[min(nxt * TE + tid, E - 1)];
        }

        // h = relu(ea @ W1^T + b1) -> bf16 hi/lo into sA
        {
            float hacc[4][3];
            #pragma unroll
            for (int i = 0; i < 4; ++i) {
                hacc[i][0] = sb1[c]; hacc[i][1] = sb1[c + 32]; hacc[i][2] = sb1[c + 64];
            }
            #pragma unroll
            for (int k0 = 0; k0 < 20; k0 += 4) {
                float4 w0 = *(const float4*)&sW1[c][k0];
                float4 w1 = *(const float4*)&sW1[c + 32][k0];
                float4 w2 = *(const float4*)&sW1[c + 64][k0];
                #pragma unroll
                for (int i = 0; i < 4; ++i) {
                    float4 av = *(const float4*)&sea[g * 4 + i][k0];
                    hacc[i][0] = fmaf(av.w, w0.w, fmaf(av.z, w0.z, fmaf(av.y, w0.y, fmaf(av.x, w0.x, hacc[i][0]))));
                    hacc[i][1] = fmaf(av.w, w1.w, fmaf(av.z, w1.z, fmaf(av.y, w1.y, fmaf(av.x, w1.x, hacc[i][1]))));
                    hacc[i][2] = fmaf(av.w, w2.w, fmaf(av.z, w2.z, fmaf(av.y, w2.y, fmaf(av.x, w2.x, hacc[i][2]))));
                }
            }
            #pragma unroll
            for (int i = 0; i < 4; ++i) {
                int e = g * 4 + i;
                #pragma unroll
                for (int j = 0; j < 3; ++j) {
                    float v = fmaxf(hacc[i][j], 0.f);
                    unsigned short hb = f2bf(v);
                    sAh[j][e][c] = hb;
                    sAl[j][e][c] = f2bf(v - bf2f(hb));
                }
            }
        }
        bar_sync();   // BAR1: sA visible; vmcnt rides

        // ===== Phase B =====
        f32x4 acc[3];
        #pragma unroll
        for (int t3 = 0; t3 < 3; ++t3) acc[t3] = (f32x4){0.f, 0.f, 0.f, 0.f};
        const int arow = mr * 16 + l15;
        #pragma unroll
        for (int chunk = 0; chunk < 3; ++chunk) {
            s16x8 a_hi = *(const s16x8*)&sAh[chunk][arow][l4 * 8];
            s16x8 a_lo = *(const s16x8*)&sAl[chunk][arow][l4 * 8];
            #pragma unroll
            for (int t3 = 0; t3 < 3; ++t3) {
                const int base = (((ng * 3 + t3) * 3 + chunk) * 64 + lane) * 8;
                s16x8 b_hi = *(const s16x8*)&sBh[base];
                s16x8 b_lo = *(const s16x8*)&sBl[base];
                acc[t3] = __builtin_amdgcn_mfma_f32_16x16x32_bf16(a_hi, b_hi, acc[t3], 0, 0, 0);
                acc[t3] = __builtin_amdgcn_mfma_f32_16x16x32_bf16(a_hi, b_lo, acc[t3], 0, 0, 0);
                acc[t3] = __builtin_amdgcn_mfma_f32_16x16x32_bf16(a_lo, b_hi, acc[t3], 0, 0, 0);
            }
        }

        // stage tile t+1 (counted vmcnt: waits prefetch, drains gathers; atomics later)
        if (nxt < ntiles) {
            sea[pe][ps]     = pf0;
            sea[pe][ps + 8] = pf1;
            if (ps == 0) sea[pe][16] = pf2;
            if (tid < TE) {
                int e = nxt * TE + tid;
                s_dst[tid] = (e < E) ? (int)(pk >> 16) : -1;
                s_src[tid] = (int)(pk & 0xFFFFu);
            }
        }

        // messages + register segmented merge + flush (atomics ride across BAR2)
        float v[3][4];
        #pragma unroll
        for (int t3 = 0; t3 < 3; ++t3)
            #pragma unroll
            for (int j = 0; j < 4; ++j)
                v[t3][j] = (acc[t3][j] + bias[t3]) * xg[t3 * 4 + j];

        if (dFirst == dLast) {
            // 16-edge group uniform (sorted => first==last suffices); wave-uniform branch
            if (dFirst >= 0) {
                #pragma unroll
                for (int t3 = 0; t3 < 3; ++t3) {
                    float s4 = (v[t3][0] + v[t3][1]) + (v[t3][2] + v[t3][3]);
                    s4 += __shfl_xor(s4, 16, 64);
                    s4 += __shfl_xor(s4, 32, 64);
                    if (l4 == 0)
                        atomicAdd(&agg[(size_t)dFirst * 96 + dv[t3]], s4);
                }
            }
        } else {
            #pragma unroll
            for (int t3 = 0; t3 < 3; ++t3) {
                float a = v[t3][0]; int cd = dj[0];
                #pragma unroll
                for (int j = 1; j < 4; ++j) {
                    if (dj[j] == cd) a += v[t3][j];
                    else {
                        if (cd >= 0) atomicAdd(&agg[(size_t)cd * 96 + dv[t3]], a);
                        a = v[t3][j]; cd = dj[j];
                    }
                }
                if (cd >= 0) atomicAdd(&agg[(size_t)cd * 96 + dv[t3]], a);
            }
        }

        bar_sync();   // BAR2
    }
}

// ---------------------------------------------------------------------------
// Fallback edge kernel (round-3 style, proven): used only if ws too small.
// ---------------------------------------------------------------------------
__global__ __launch_bounds__(512, 4) void edge_kernel_atomic(
    const float* __restrict__ x, const int* __restrict__ ei,
    const float* __restrict__ ea, const float* __restrict__ W1,
    const float* __restrict__ b1, const float* __restrict__ W2,
    const float* __restrict__ b2, float* __restrict__ agg, int N, int E)
{
    __shared__ unsigned short sBh[9216], sBl[9216];
    __shared__ unsigned short sAh[3][64][40], sAl[3][64][40];
    __shared__ float sW1[96][20];
    __shared__ float sea[64][20];
    __shared__ float sb1[96];
    __shared__ int   ssrc[64], sdst[64];

    const int tid = threadIdx.x;
    const int c = tid & 31, g = tid >> 5;
    const int lane = tid & 63, wv = tid >> 6;
    const int mr = wv & 3, ng = wv >> 2;
    const int l15 = lane & 15, l4 = lane >> 4;
    const int ntiles = (E + 63) / 64;

    for (int idx = tid; idx < 96 * 20; idx += 512) {
        int d = idx / 20, k = idx - d * 20;
        sW1[d][k] = (k < 17) ? W1[d * 17 + k] : 0.f;
    }
    for (int idx = tid; idx < 96 * 96; idx += 512) {
        int d = idx / 96, k = idx - d * 96;
        float v = W2[idx];
        unsigned short hb = f2bf(v);
        int ngf = d / 48, tt = (d % 48) / 16, r = d & 15;
        int ch = k >> 5, kl4 = (k & 31) >> 3, sb = k & 7;
        int fo = ((((ngf * 3 + tt) * 3 + ch) * 4 + kl4) * 16 + r) * 8 + sb;
        sBh[fo] = hb; sBl[fo] = f2bf(v - bf2f(hb));
    }
    if (tid < 96) sb1[tid] = b1[tid];
    float bias[3]; int dv[3];
    #pragma unroll
    for (int t = 0; t < 3; ++t) { dv[t] = (ng * 3 + t) * 16 + l15; bias[t] = b2[dv[t]]; }

    for (int tile = blockIdx.x; tile < ntiles; tile += 512) {
        const int e0 = tile * 64;
        __syncthreads();
        for (int idx = tid; idx < 64 * 20; idx += 512) {
            int e = idx / 20, k = idx - e * 20;
            float v = 0.f;
            if (k < 17 && e0 + e < E) v = ea[(size_t)(e0 + e) * 17 + k];
            sea[e][k] = v;
        }
        if (tid < 64) {
            int e = e0 + tid;
            ssrc[tid] = (e < E) ? ei[e] : 0;
            sdst[tid] = (e < E) ? ei[E + e] : 0;
        }
        __syncthreads();
        {
            float hacc[4][3];
            #pragma unroll
            for (int i = 0; i < 4; ++i) { hacc[i][0]=sb1[c]; hacc[i][1]=sb1[c+32]; hacc[i][2]=sb1[c+64]; }
            #pragma unroll
            for (int k0 = 0; k0 < 20; k0 += 4) {
                float4 w0 = *(const float4*)&sW1[c][k0];
                float4 w1 = *(const float4*)&sW1[c + 32][k0];
                float4 w2 = *(const float4*)&sW1[c + 64][k0];
                #pragma unroll
                for (int i = 0; i < 4; ++i) {
                    float4 av = *(const float4*)&sea[g * 4 + i][k0];
                    hacc[i][0] = fmaf(av.w, w0.w, fmaf(av.z, w0.z, fmaf(av.y, w0.y, fmaf(av.x, w0.x, hacc[i][0]))));
                    hacc[i][1] = fmaf(av.w, w1.w, fmaf(av.z, w1.z, fmaf(av.y, w1.y, fmaf(av.x, w1.x, hacc[i][1]))));
                    hacc[i][2] = fmaf(av.w, w2.w, fmaf(av.z, w2.z, fmaf(av.y, w2.y, fmaf(av.x, w2.x, hacc[i][2]))));
                }
            }
            #pragma unroll
            for (int i = 0; i < 4; ++i) {
                int e = g * 4 + i;
                #pragma unroll
                for (int j = 0; j < 3; ++j) {
                    float v = fmaxf(hacc[i][j], 0.f);
                    unsigned short hb = f2bf(v);
                    sAh[j][e][c] = hb; sAl[j][e][c] = f2bf(v - bf2f(hb));
                }
            }
        }
        __syncthreads();
        f32x4 acc[3];
        #pragma unroll
        for (int t = 0; t < 3; ++t) acc[t] = (f32x4){0.f, 0.f, 0.f, 0.f};
        const int arow = mr * 16 + l15;
        #pragma unroll
        for (int chunk = 0; chunk < 3; ++chunk) {
            s16x8 a_hi = *(const s16x8*)&sAh[chunk][arow][l4 * 8];
            s16x8 a_lo = *(const s16x8*)&sAl[chunk][arow][l4 * 8];
            #pragma unroll
            for (int t = 0; t < 3; ++t) {
                const int base = (((ng * 3 + t) * 3 + chunk) * 64 + lane) * 8;
                s16x8 b_hi = *(const s16x8*)&sBh[base];
                s16x8 b_lo = *(const s16x8*)&sBl[base];
                acc[t] = __builtin_amdgcn_mfma_f32_16x16x32_bf16(a_hi, b_hi, acc[t], 0, 0, 0);
                acc[t] = __builtin_amdgcn_mfma_f32_16x16x32_bf16(a_hi, b_lo, acc[t], 0, 0, 0);
                acc[t] = __builtin_amdgcn_mfma_f32_16x16x32_bf16(a_lo, b_hi, acc[t], 0, 0, 0);
            }
        }
        #pragma unroll
        for (int t = 0; t < 3; ++t)
            #pragma unroll
            for (int j = 0; j < 4; ++j) {
                int el = mr * 16 + l4 * 4 + j;
                int e  = e0 + el;
                if (e < E) {
                    int s = ssrc[el], dn = sdst[el];
                    atomicAdd(&agg[(size_t)dn * 96 + dv[t]],
                              (acc[t][j] + bias[t]) * x[(size_t)s * 96 + dv[t]]);
                }
            }
    }
}

// ---------------------------------------------------------------------------
// Node kernel: out = relu(x @ Ws^T + bs + agg @ Wn^T + bn); agg may alias out.
// ---------------------------------------------------------------------------
__global__ __launch_bounds__(BLOCK, 4) void node_kernel(
    const float* __restrict__ x,
    const float* agg,
    const float* __restrict__ Ws, const float* __restrict__ bs,
    const float* __restrict__ Wn, const float* __restrict__ bn,
    float* out, int N)
{
    __shared__ float sW[96][100];
    __shared__ float sxa[TN][100];
    __shared__ float sbias[96];

    const int tid = threadIdx.x;
    const int c = tid & 31, g = tid >> 5;
    const int n0 = blockIdx.x * TN;

    if (tid < 96) sbias[tid] = bs[tid] + bn[tid];

    float acc[4][3];
    #pragma unroll
    for (int i = 0; i < 4; ++i)
        for (int j = 0; j < 3; ++j) acc[i][j] = 0.f;

    for (int ph = 0; ph < 2; ++ph) {
        const float* W   = ph ? Wn : Ws;
        const float* src = ph ? agg : x;
        __syncthreads();
        for (int idx = tid; idx < 96 * 24; idx += BLOCK) {
            int d = idx / 24, kq = idx - d * 24;
            *(float4*)&sW[d][kq * 4] = *(const float4*)&W[d * 96 + kq * 4];
        }
        for (int idx = tid; idx < TN * 24; idx += BLOCK) {
            int n = idx / 24, kq = idx - n * 24;
            float4 v = make_float4(0.f, 0.f, 0.f, 0.f);
            if (n0 + n < N) v = *(const float4*)&src[(size_t)(n0 + n) * 96 + kq * 4];
            *(float4*)&sxa[n][kq * 4] = v;
        }
        __syncthreads();
        #pragma unroll 2
        for (int k0 = 0; k0 < 96; k0 += 4) {
            float4 w0 = *(const float4*)&sW[c][k0];
            float4 w1 = *(const float4*)&sW[c + 32][k0];
            float4 w2 = *(const float4*)&sW[c + 64][k0];
            #pragma unroll
            for (int i = 0; i < 4; ++i) {
                float4 xv = *(const float4*)&sxa[g * 4 + i][k0];
                acc[i][0] = fmaf(xv.w, w0.w, fmaf(xv.z, w0.z, fmaf(xv.y, w0.y, fmaf(xv.x, w0.x, acc[i][0]))));
                acc[i][1] = fmaf(xv.w, w1.w, fmaf(xv.z, w1.z, fmaf(xv.y, w1.y, fmaf(xv.x, w1.x, acc[i][1]))));
                acc[i][2] = fmaf(xv.w, w2.w, fmaf(xv.z, w2.z, fmaf(xv.y, w2.y, fmaf(xv.x, w2.x, acc[i][2]))));
            }
        }
    }

    #pragma unroll
    for (int i = 0; i < 4; ++i) {
        int n = n0 + g * 4 + i;
        if (n < N) {
            out[(size_t)n * 96 + c]      = fmaxf(acc[i][0] + sbias[c], 0.f);
            out[(size_t)n * 96 + c + 32] = fmaxf(acc[i][1] + sbias[c + 32], 0.f);
            out[(size_t)n * 96 + c + 64] = fmaxf(acc[i][2] + sbias[c + 64], 0.f);
        }
    }
}

extern "C" void kernel_launch(void* const* d_in, const int* in_sizes, int n_in,
                              void* d_out, int out_size, void* d_ws, size_t ws_size,
                              hipStream_t stream) {
    const float* x  = (const float*)d_in[0];
    const int*   ei = (const int*)d_in[1];
    const float* ea = (const float*)d_in[2];
    const float* W1 = (const float*)d_in[3];
    const float* b1 = (const float*)d_in[4];
    const float* W2 = (const float*)d_in[5];
    const float* b2 = (const float*)d_in[6];
    const float* Ws = (const float*)d_in[7];
    const float* bs = (const float*)d_in[8];
    const float* Wn = (const float*)d_in[9];
    const float* bn = (const float*)d_in[10];
    float* out = (float*)d_out;

    const int N = in_sizes[0] / 96;
    const int E = in_sizes[2] / 17;

    const size_t need = (size_t)N * 4 + (size_t)E * 4 + (size_t)E * 17 * 4;
    // agg accumulates in d_out (node_kernel reads its rows before overwriting)
    hipMemsetAsync(out, 0, (size_t)N * 96 * sizeof(float), stream);

    if (ws_size >= need) {
        int*      cur    = (int*)d_ws;             // [N]
        unsigned* packed = (unsigned*)(cur + N);   // [E]
        float*    ea_s   = (float*)(packed + E);   // [E*17]

        hipMemsetAsync(cur, 0, (size_t)N * sizeof(int), stream);
        hist_kernel<<<(E + 255) / 256, 256, 0, stream>>>(ei, cur, E);
        scan_kernel<<<1, 1024, 0, stream>>>(cur, N);
        scatter_kernel<<<(E * 8 + 511) / 512, 512, 0, stream>>>(ei, ea, cur, packed, ea_s, E);
        edge_sorted_kernel<<<NTB, BLOCK, 0, stream>>>(
            x, packed, ea_s, W1, b1, W2, b2, out, N, E);
    } else {
        edge_kernel_atomic<<<512, 512, 0, stream>>>(x, ei, ea, W1, b1, W2, b2, out, N, E);
    }
    node_kernel<<<(N + TN - 1) / TN, BLOCK, 0, stream>>>(x, out, Ws, bs, Wn, bn, out, N);
}